// Round 8
// baseline (107.151 us; speedup 1.0000x reference)
//
#include <hip/hip_runtime.h>

// VecLocal2d via MFMA, R8: barrier-free, LDS-free main kernel.
// R4-R7 post-mortem: every barrier-synced per-pixel phase structure cost
// ~10us/pixel-phase regardless of micro-optimization. R8 removes the sync
// structure: wave = (pixel, bk-half), 2048 fully independent waves.
//   - B (W) operand: with f' = cell*32 + c, a lane's share of its o-row is
//     72 CONSECUTIVE floats in global w -> 18x float4 loads, convert to
//     bf16 frags in-register (L1-resident sectors, W read from HBM once).
//   - A operand: dense 16B loads from xc[(ih)][(jw)][bk][c] (L3-resident).
//   - Two nt-group passes (nt{0,1}, nt{2,3}) keep VGPR ~200 (A read 2x).
//   - Output via co[pix][o][bk] bf16 + t2 transpose/bias kernel (proven).
//
// Pipeline (fast path, ~31.3 MB ws): hz -> t1 -> main -> t2.
// Fallback (ws < 31.3 MB): R3 path (proven, 10 MB).

#define HW    32
#define CIN   32
#define COUT  64
#define FDIM  288
#define FPAD  296
#define NBK   160
#define HP    34
#define PLANE (NBK * CIN)   // 5120 shorts per (ih,jw) plane

using f32x4  = __attribute__((ext_vector_type(4))) float;
using bf16x8 = __attribute__((ext_vector_type(8))) short;
using s16x4  = __attribute__((ext_vector_type(4))) short;

static __device__ inline unsigned short f2bf(float f) {
    unsigned u = __float_as_uint(f);
    u += 0x7FFFu + ((u >> 16) & 1u);   // round-to-nearest-even
    return (unsigned short)(u >> 16);
}
static constexpr size_t XC_BYTES = (size_t)HP * HP * PLANE * 2;       // 11,837,440
static constexpr size_t CO_BYTES = (size_t)1024 * COUT * NBK * 2;     // 20,971,520

// ---- hz: zero the 132 halo planes ----
__global__ __launch_bounds__(256) void hz_kernel(short* __restrict__ xc)
{
    const int id = blockIdx.x;           // 0..131
    int h, w;
    if (id < 34)      { h = 0;  w = id; }
    else if (id < 68) { h = 33; w = id - 34; }
    else { const int e = id - 68; h = 1 + (e >> 1); w = (e & 1) * 33; }
    uint2* p = reinterpret_cast<uint2*>(xc + (size_t)(h * HP + w) * PLANE);
    const uint2 z = {0u, 0u};
#pragma unroll
    for (int r = 0; r < 5; ++r)
        p[threadIdx.x + r * 256] = z;
}

// ---- t1: x [bk][c][h][w] fp32 -> xc [h+1][w+1][bk][c] bf16 (linear) ----
__global__ __launch_bounds__(256) void t1_kernel(
    const float* __restrict__ x, short* __restrict__ xc)
{
    __shared__ short tile[HW][36];
    const int bid = blockIdx.x;      // 5120 = bk(160) * h(32)
    const int bk  = bid >> 5;
    const int h   = bid & 31;
    const int tid = threadIdx.x;
    {
        const int c  = tid >> 3;
        const int w4 = (tid & 7) * 4;
        const float4 v = *reinterpret_cast<const float4*>(
            x + (size_t)(bk * 32 + c) * 1024 + h * 32 + w4);
        tile[w4 + 0][c] = (short)f2bf(v.x);
        tile[w4 + 1][c] = (short)f2bf(v.y);
        tile[w4 + 2][c] = (short)f2bf(v.z);
        tile[w4 + 3][c] = (short)f2bf(v.w);
    }
    __syncthreads();
    {
        const int w  = tid >> 3;
        const int cq = tid & 7;
        const uint2 pk = *reinterpret_cast<const uint2*>(&tile[w][cq * 4]);
        *reinterpret_cast<uint2*>(
            xc + (size_t)((h + 1) * HP + (w + 1)) * PLANE + bk * CIN + cq * 4) = pk;
    }
}

// ---- main: barrier-free. wave = (pixel, bk-half); 256 blocks x 512 thr ----
__global__ __launch_bounds__(512) void local2d_g_kernel(
    const short* __restrict__ xc,
    const float* __restrict__ w,
    short* __restrict__ co)
{
    const int hb  = blockIdx.x;          // 256 = i(32) * jt(8)
    const int i   = hb >> 3;
    const int jt  = hb & 7;
    const int tid = threadIdx.x;
    const int wid = tid >> 6;            // 0..7
    const int lane = tid & 63;
    const int p   = wid >> 1;            // pixel within j-tile, 0..3
    const int mh  = wid & 1;             // bk-half
    const int j   = jt * 4 + p;
    const int pix = i * HW + j;
    const int l15 = lane & 15;
    const int lg  = lane >> 4;
    const int lg8 = lg * 8;

    // A base: xc interior plane (i,j), this lane's (bk,c) slot
    const short* abase = xc + ((size_t)i * HP + j) * PLANE
                            + (mh * 80 + l15) * CIN + lg8;

    f32x4 acc[5][4];
#pragma unroll
    for (int mt = 0; mt < 5; ++mt)
#pragma unroll
        for (int nt = 0; nt < 4; ++nt)
#pragma unroll
            for (int r = 0; r < 4; ++r) acc[mt][nt][r] = 0.f;

#pragma unroll
    for (int g = 0; g < 2; ++g) {
        // ---- load + convert W frags for nt = 2g, 2g+1 (held in regs) ----
        bf16x8 wfr[2][9];
#pragma unroll
        for (int ntl = 0; ntl < 2; ++ntl) {
            const int nt = g * 2 + ntl;
            // lane's 72 consecutive floats of row o = nt*16+l15
            const float* q = w + ((size_t)pix * COUT + nt * 16 + l15) * FDIM
                               + lg8 * 9;
            float t[72];
#pragma unroll
            for (int r = 0; r < 18; ++r)
                *reinterpret_cast<float4*>(&t[r * 4]) =
                    *reinterpret_cast<const float4*>(q + r * 4);
#pragma unroll
            for (int kc = 0; kc < 9; ++kc) {
                bf16x8 f;
#pragma unroll
                for (int e = 0; e < 8; ++e)
                    f[e] = (short)f2bf(t[e * 9 + kc]);   // f' elem = (c=lg8+e, cell=kc)
                wfr[ntl][kc] = f;
            }
        }

        // ---- kc loop: dense A loads + 10 mfma per kc ----
#pragma unroll
        for (int kc = 0; kc < 9; ++kc) {
            const int kh = kc / 3;
            const int kw = kc - kh * 3;
            const short* ap = abase + (kh * HP + kw) * PLANE;
            bf16x8 afr[5];
#pragma unroll
            for (int mt = 0; mt < 5; ++mt)
                afr[mt] = *reinterpret_cast<const bf16x8*>(ap + mt * 16 * CIN);
#pragma unroll
            for (int ntl = 0; ntl < 2; ++ntl) {
                const int nt = g * 2 + ntl;
#pragma unroll
                for (int mt = 0; mt < 5; ++mt)
                    acc[mt][nt] = __builtin_amdgcn_mfma_f32_16x16x32_bf16(
                        afr[mt], wfr[ntl][kc], acc[mt][nt], 0, 0, 0);
            }
        }
    }

    // ---- store: co[pix][o][bk] bf16, 8B per store ----
#pragma unroll
    for (int nt = 0; nt < 4; ++nt) {
        const int o = nt * 16 + l15;
        const size_t cb = ((size_t)pix * COUT + o) * NBK + mh * 80 + lg * 4;
#pragma unroll
        for (int mt = 0; mt < 5; ++mt) {
            s16x4 s;
            s.x = (short)f2bf(acc[mt][nt][0]); s.y = (short)f2bf(acc[mt][nt][1]);
            s.z = (short)f2bf(acc[mt][nt][2]); s.w = (short)f2bf(acc[mt][nt][3]);
            *reinterpret_cast<s16x4*>(co + cb + mt * 16) = s;
        }
    }
}

// ---- t2: out[bk][o][pix] = f32(co[pix][o][bk]) + bias[bk%10][o][pix] ----
__global__ __launch_bounds__(256) void t2_kernel(
    const short* __restrict__ co,
    const float* __restrict__ bias,
    float* __restrict__ out)
{
    __shared__ short tl[32][36];
    const int b    = blockIdx.x;          // 10240 = o(64) * bkT(5) * pixT(32)
    const int o    = b & 63;
    const int rest = b >> 6;
    const int bkT  = rest % 5;
    const int pixT = rest / 5;
    const int tid  = threadIdx.x;
    {
        const int p  = tid >> 3;
        const int bq = tid & 7;
        const int pix = pixT * 32 + p;
        const s16x4 v = *reinterpret_cast<const s16x4*>(
            co + ((size_t)pix * COUT + o) * NBK + bkT * 32 + bq * 4);
        *reinterpret_cast<s16x4*>(&tl[p][bq * 4]) = v;
    }
    __syncthreads();
    {
        const int bb = tid >> 3;
        const int pq = tid & 7;
        const int bk = bkT * 32 + bb;
        const int k  = bk % 10;
        const size_t pbase = (size_t)pixT * 32 + pq * 4;
        const float4 bv = *reinterpret_cast<const float4*>(
            bias + ((size_t)(k * COUT + o) << 10) + pbase);
        float4 r;
        r.x = __uint_as_float(((unsigned)(unsigned short)tl[pq * 4 + 0][bb]) << 16) + bv.x;
        r.y = __uint_as_float(((unsigned)(unsigned short)tl[pq * 4 + 1][bb]) << 16) + bv.y;
        r.z = __uint_as_float(((unsigned)(unsigned short)tl[pq * 4 + 2][bb]) << 16) + bv.z;
        r.w = __uint_as_float(((unsigned)(unsigned short)tl[pq * 4 + 3][bb]) << 16) + bv.w;
        *reinterpret_cast<float4*>(out + ((size_t)(bk * COUT + o) << 10) + pbase) = r;
    }
}

// ================= R3 fallback (proven; needs 10 MB ws) =================
__global__ __launch_bounds__(256) void xpose_kernel(
    const float* __restrict__ x, short* __restrict__ xc)
{
    __shared__ short tile[HW][36];
    const int bid = blockIdx.x;
    const int bk  = bid >> 5;
    const int h   = bid & 31;
    const int tid = threadIdx.x;
    {
        const int c  = tid >> 3;
        const int w4 = (tid & 7) * 4;
        const float4 v = *reinterpret_cast<const float4*>(
            x + (size_t)(bk * 32 + c) * 1024 + h * 32 + w4);
        tile[w4 + 0][c] = (short)f2bf(v.x);
        tile[w4 + 1][c] = (short)f2bf(v.y);
        tile[w4 + 2][c] = (short)f2bf(v.z);
        tile[w4 + 3][c] = (short)f2bf(v.w);
    }
    __syncthreads();
    {
        const int w  = tid >> 3;
        const int cq = tid & 7;
        const uint2 pk = *reinterpret_cast<const uint2*>(&tile[w][cq * 4]);
        *reinterpret_cast<uint2*>(
            xc + ((size_t)(bk * 1024 + h * 32 + w) * 32 + cq * 4)) = pk;
    }
}

__global__ __launch_bounds__(512, 4) void local2d_mfma2_kernel(
    const short* __restrict__ xc,
    const float* __restrict__ w,
    const float* __restrict__ bias,
    float* __restrict__ out)
{
    __shared__ short Wl[COUT * FPAD];
    const int hb  = blockIdx.x;
    const int lb  = (hb & 7) * 128 + (hb >> 3);
    const int i   = lb >> 5;
    const int j   = lb & 31;
    const int pix = i * HW + j;
    const int tid = threadIdx.x;
    {
        const float* wp = w + (size_t)pix * (COUT * FDIM);
#pragma unroll
        for (int p = 0; p < 9; ++p) {
            const int g  = tid + p * 512;
            const int o  = g / 72;
            const int f4 = (g - o * 72) * 4;
            const float4 v = *reinterpret_cast<const float4*>(wp + o * FDIM + f4);
            const float vv[4] = {v.x, v.y, v.z, v.w};
            short* wrow = &Wl[o * FPAD];
#pragma unroll
            for (int e = 0; e < 4; ++e) {
                const int f    = f4 + e;
                const int c    = f / 9;
                const int cell = f - c * 9;
                wrow[cell * 32 + c] = (short)f2bf(vv[e]);
            }
        }
    }
    __syncthreads();
    const int wave = tid >> 6;
    const int lane = tid & 63;
    const int nt   = wave & 3;
    const int mh   = wave >> 2;
    const int l15  = lane & 15;
    const int lg8  = (lane >> 4) * 8;
    f32x4 acc[5];
#pragma unroll
    for (int mt = 0; mt < 5; ++mt)
#pragma unroll
        for (int r = 0; r < 4; ++r) acc[mt][r] = 0.f;
    const short* xb[5];
#pragma unroll
    for (int mt = 0; mt < 5; ++mt) {
        const int bk = mh * 80 + mt * 16 + l15;
        xb[mt] = xc + (size_t)bk * (HW * HW * CIN) + lg8;
    }
    const short* bp = &Wl[(nt * 16 + l15) * FPAD + lg8];
#pragma unroll
    for (int kc = 0; kc < 9; ++kc) {
        const int kh = kc / 3;
        const int kw = kc - kh * 3;
        const int ih = i - 1 + kh;
        const int jw = j - 1 + kw;
        if ((unsigned)ih >= (unsigned)HW || (unsigned)jw >= (unsigned)HW)
            continue;
        const bf16x8 b = *reinterpret_cast<const bf16x8*>(bp + kc * 32);
        const int xoff = (ih * HW + jw) * CIN;
#pragma unroll
        for (int mt = 0; mt < 5; ++mt) {
            const bf16x8 a = *reinterpret_cast<const bf16x8*>(xb[mt] + xoff);
            acc[mt] = __builtin_amdgcn_mfma_f32_16x16x32_bf16(a, b, acc[mt], 0, 0, 0);
        }
    }
    const int o  = nt * 16 + l15;
    const int r0 = (lane >> 4) * 4;
#pragma unroll
    for (int mt = 0; mt < 5; ++mt) {
        const int bk0 = mh * 80 + mt * 16 + r0;
#pragma unroll
        for (int r = 0; r < 4; ++r) {
            const int bk = bk0 + r;
            const int k  = bk % 10;
            out[((size_t)(bk * COUT + o) << 10) + pix] =
                acc[mt][r] + bias[((size_t)(k * COUT + o) << 10) + pix];
        }
    }
}

extern "C" void kernel_launch(void* const* d_in, const int* in_sizes, int n_in,
                              void* d_out, int out_size, void* d_ws, size_t ws_size,
                              hipStream_t stream) {
    const float* x    = (const float*)d_in[0];
    const float* w    = (const float*)d_in[1];
    const float* bias = (const float*)d_in[2];
    float* out        = (float*)d_out;

    if (ws_size >= XC_BYTES + CO_BYTES) {
        short* xc = (short*)d_ws;
        short* co = (short*)((char*)d_ws + XC_BYTES);
        hipLaunchKernelGGL(hz_kernel, dim3(132), dim3(256), 0, stream, xc);
        hipLaunchKernelGGL(t1_kernel, dim3(5120), dim3(256), 0, stream, x, xc);
        hipLaunchKernelGGL(local2d_g_kernel, dim3(256), dim3(512), 0, stream,
                           xc, w, co);
        hipLaunchKernelGGL(t2_kernel, dim3(10240), dim3(256), 0, stream,
                           co, bias, out);
    } else {
        short* xc = (short*)d_ws;
        hipLaunchKernelGGL(xpose_kernel, dim3(5120), dim3(256), 0, stream, x, xc);
        hipLaunchKernelGGL(local2d_mfma2_kernel, dim3(1024), dim3(512), 0, stream,
                           xc, w, bias, out);
    }
}

// Round 9
// 51.094 us; speedup vs baseline: 2.0971x; 2.0971x over previous
//
#include <hip/hip_runtime.h>

// VecLocal2d via MFMA, R9 = R7 + counted-vmcnt raw-barrier pipeline (T3/T4).
// R7's __syncthreads() drained vmcnt(0) each phase, serially exposing the
// 73.7 KB/pixel W stream (the m97 barrier-drain stall). R9 uses raw
// s_barrier + counted s_waitcnt so W(p+1) stays in flight across barriers.
//
// Schedule (per wave; vmcnt audits in brackets, issue order pinned by
// sched_barrier(0)):
//  prologue: issue W0[9]; issue SLOTS[15]; vm(15){W0 done}; scatter0;
//            issue W1[9]; vm(9){S done}; lgkm0+BAR
//  ph0: compute0(slots 0,1,2); store0; BAR; vm(0){W1}; scatter1;
//       issue W2[9]; lgkm0+BAR
//  ph1: issue R0[4](col j0+4->slot0); compute1(1,2,3); store1; BAR;
//       vm(4){W2}; scatter2; issue W3[9]; vm(9){R0}; lgkm0+BAR
//  ph2: issue R1[4](col j0+5->slot1); compute2(2,3,0); store2; BAR;
//       vm(4){W3}; scatter3; vm(0){R1}; lgkm0+BAR
//  ph3: compute3(3,0,1); store3
// Cross-wave gl_lds rule: each wave vm-completes its own gl_lds BEFORE the
// barrier preceding the consuming compute; barrier then publishes.
//
// Everything else (hz, t1 pre-swizzled, compute/scatter/store bodies, t2,
// R3 fallback) verbatim from R7 (passed, absmax 0.03125).

#define HW    32
#define CIN   32
#define COUT  64
#define FDIM  288
#define FPAD  296
#define NBK   160
#define HP    34
#define PLANE (NBK * CIN)      // 5120 shorts per (ih,jw) plane
#define SLOT_SH (3 * PLANE)    // 15360 shorts per jw-slot
#define WOFF  (4 * SLOT_SH)    // 61440 shorts: W region start

using f32x4  = __attribute__((ext_vector_type(4))) float;
using bf16x8 = __attribute__((ext_vector_type(8))) short;
using s16x4  = __attribute__((ext_vector_type(4))) short;

static __device__ inline unsigned short f2bf(float f) {
    unsigned u = __float_as_uint(f);
    u += 0x7FFFu + ((u >> 16) & 1u);   // round-to-nearest-even
    return (unsigned short)(u >> 16);
}
static __device__ inline void gl_lds16(const short* src, short* dst) {
    __builtin_amdgcn_global_load_lds(
        (const __attribute__((address_space(1))) unsigned int*)src,
        (__attribute__((address_space(3))) unsigned int*)dst, 16, 0, 0);
}
static constexpr size_t XC_BYTES = (size_t)HP * HP * PLANE * 2;       // 11,837,440
static constexpr size_t CO_BYTES = (size_t)1024 * COUT * NBK * 2;     // 20,971,520

// ---- hz ----
__global__ __launch_bounds__(256) void hz_kernel(short* __restrict__ xc)
{
    const int id = blockIdx.x;
    int h, w;
    if (id < 34)      { h = 0;  w = id; }
    else if (id < 68) { h = 33; w = id - 34; }
    else { const int e = id - 68; h = 1 + (e >> 1); w = (e & 1) * 33; }
    uint2* p = reinterpret_cast<uint2*>(xc + (size_t)(h * HP + w) * PLANE);
    const uint2 z = {0u, 0u};
#pragma unroll
    for (int r = 0; r < 5; ++r)
        p[threadIdx.x + r * 256] = z;
}

// ---- t1 (pre-swizzled planes) ----
__global__ __launch_bounds__(256) void t1_kernel(
    const float* __restrict__ x, short* __restrict__ xc)
{
    __shared__ short tile[HW][36];
    const int bid = blockIdx.x;
    const int bk  = bid >> 5;
    const int h   = bid & 31;
    const int tid = threadIdx.x;
    {
        const int c  = tid >> 3;
        const int w4 = (tid & 7) * 4;
        const float4 v = *reinterpret_cast<const float4*>(
            x + (size_t)(bk * 32 + c) * 1024 + h * 32 + w4);
        tile[w4 + 0][c] = (short)f2bf(v.x);
        tile[w4 + 1][c] = (short)f2bf(v.y);
        tile[w4 + 2][c] = (short)f2bf(v.z);
        tile[w4 + 3][c] = (short)f2bf(v.w);
    }
    __syncthreads();
    {
        const int w  = tid >> 3;
        const int cq = tid & 7;
        const uint2 pk = *reinterpret_cast<const uint2*>(&tile[w][cq * 4]);
        const int sidx = bk * 32 + ((cq * 4) ^ (((bk >> 1) & 3) << 3));
        *reinterpret_cast<uint2*>(
            xc + (size_t)((h + 1) * HP + (w + 1)) * PLANE + sidx) = pk;
    }
}

// ---- main: counted-vmcnt pipelined ----
#define SB()  __builtin_amdgcn_sched_barrier(0)
#define VM(n) { asm volatile("s_waitcnt vmcnt(" #n ")" ::: "memory"); SB(); }
#define LG0BAR() { asm volatile("s_waitcnt lgkmcnt(0)" ::: "memory"); SB(); \
                   __builtin_amdgcn_s_barrier(); SB(); }
#define BARA() { asm volatile("s_waitcnt lgkmcnt(0)" ::: "memory"); SB(); \
                 __builtin_amdgcn_s_barrier(); SB(); }

__global__ __launch_bounds__(512) void local2d_p_kernel(
    const short* __restrict__ xc,
    const float* __restrict__ w,
    short* __restrict__ co)
{
    __shared__ __align__(1024) short Sl[WOFF + COUT * FPAD];  // 160,768 B

    const int hb = blockIdx.x;                  // 256 = i(32) * jt(8)
    const int lb = (hb & 7) * 32 + (hb >> 3);   // XCD-chunked, bijective
    const int i  = lb >> 3;
    const int jt = lb & 7;
    const int j0 = jt * 4;
    const int tid = threadIdx.x;

    const int wave = tid >> 6;
    const int lane = tid & 63;
    const int nt   = wave & 3;
    const int mh   = wave >> 2;
    const int l15  = lane & 15;
    const int lg   = lane >> 4;
    const int lg8  = lg * 8;

    short* WL = Sl + WOFF;

    int rowbyte[5];
#pragma unroll
    for (int mt = 0; mt < 5; ++mt) {
        const int bk = mh * 80 + mt * 16 + l15;
        rowbyte[mt] = (bk * 64 + lg * 16) ^ (((bk >> 1) & 3) << 4);
    }

    float4 wv0[9], wv1[9];
    const f32x4 z4 = {0.f, 0.f, 0.f, 0.f};
    f32x4 acc0, acc1, acc2, acc3, acc4;

#define WISSUE(dst, pp) {                                                  \
        const float* wp = w + (size_t)((i * 32) + j0 + (pp)) * (COUT * FDIM); \
        _Pragma("unroll")                                                  \
        for (int q = 0; q < 9; ++q) {                                      \
            const int g  = tid + q * 512;                                  \
            const int o2 = g / 72;                                         \
            const int f4 = (g - o2 * 72) * 4;                              \
            dst[q] = *reinterpret_cast<const float4*>(wp + o2 * FDIM + f4);\
        } SB(); }

#define SCATTER(src) {                                                     \
        _Pragma("unroll")                                                  \
        for (int q = 0; q < 9; ++q) {                                      \
            const int g  = tid + q * 512;                                  \
            const int o2 = g / 72;                                         \
            const int f4 = (g - o2 * 72) * 4;                              \
            const float vv[4] = {src[q].x, src[q].y, src[q].z, src[q].w};  \
            short* wrow = WL + o2 * FPAD;                                  \
            _Pragma("unroll")                                              \
            for (int e = 0; e < 4; ++e) {                                  \
                const int f = f4 + e; const int c = f / 9;                 \
                const int cell = f - c * 9;                                \
                wrow[cell * 32 + c] = (short)f2bf(vv[e]); } } SB(); }

#define RISSUE(s) {                                                        \
        if (tid < 480) {                                                   \
            _Pragma("unroll")                                              \
            for (int r = 0; r < 4; ++r) {                                  \
                const int u  = tid + r * 480;                              \
                const int pl = u / 640;                                    \
                const int cu = u - pl * 640;                               \
                const short* src = xc + (size_t)((i + pl) * HP + (j0 + 4 + (s))) * PLANE + cu * 8; \
                gl_lds16(src, Sl + (size_t)((s) * SLOT_SH) + (size_t)u * 8); \
            } } SB(); }

#define COMPUTE(p) {                                                       \
        acc0 = z4; acc1 = z4; acc2 = z4; acc3 = z4; acc4 = z4;             \
        const short* bp = WL + (nt * 16 + l15) * FPAD + lg8;               \
        _Pragma("unroll")                                                  \
        for (int kc = 0; kc < 9; ++kc) {                                   \
            const int kh   = kc / 3;                                       \
            const int kw   = kc - kh * 3;                                  \
            const int slot = ((p) + kw) & 3;                               \
            const char* ab = (const char*)Sl + slot * (SLOT_SH * 2) + kh * (PLANE * 2); \
            const bf16x8 b  = *reinterpret_cast<const bf16x8*>(bp + kc * 32); \
            const bf16x8 a0 = *reinterpret_cast<const bf16x8*>(ab + rowbyte[0]); \
            const bf16x8 a1 = *reinterpret_cast<const bf16x8*>(ab + rowbyte[1]); \
            const bf16x8 a2 = *reinterpret_cast<const bf16x8*>(ab + rowbyte[2]); \
            const bf16x8 a3 = *reinterpret_cast<const bf16x8*>(ab + rowbyte[3]); \
            const bf16x8 a4 = *reinterpret_cast<const bf16x8*>(ab + rowbyte[4]); \
            acc0 = __builtin_amdgcn_mfma_f32_16x16x32_bf16(a0, b, acc0, 0, 0, 0); \
            acc1 = __builtin_amdgcn_mfma_f32_16x16x32_bf16(a1, b, acc1, 0, 0, 0); \
            acc2 = __builtin_amdgcn_mfma_f32_16x16x32_bf16(a2, b, acc2, 0, 0, 0); \
            acc3 = __builtin_amdgcn_mfma_f32_16x16x32_bf16(a3, b, acc3, 0, 0, 0); \
            acc4 = __builtin_amdgcn_mfma_f32_16x16x32_bf16(a4, b, acc4, 0, 0, 0); \
        } }

#define STORE(p) {                                                         \
        const int pix = i * 32 + j0 + (p);                                 \
        const int o3  = nt * 16 + l15;                                     \
        const size_t cb = ((size_t)pix * COUT + o3) * NBK + mh * 80 + lg * 4; \
        { s16x4 s_; s_.x = (short)f2bf(acc0[0]); s_.y = (short)f2bf(acc0[1]); \
          s_.z = (short)f2bf(acc0[2]); s_.w = (short)f2bf(acc0[3]);        \
          *reinterpret_cast<s16x4*>(co + cb + 0) = s_; }                   \
        { s16x4 s_; s_.x = (short)f2bf(acc1[0]); s_.y = (short)f2bf(acc1[1]); \
          s_.z = (short)f2bf(acc1[2]); s_.w = (short)f2bf(acc1[3]);        \
          *reinterpret_cast<s16x4*>(co + cb + 16) = s_; }                  \
        { s16x4 s_; s_.x = (short)f2bf(acc2[0]); s_.y = (short)f2bf(acc2[1]); \
          s_.z = (short)f2bf(acc2[2]); s_.w = (short)f2bf(acc2[3]);        \
          *reinterpret_cast<s16x4*>(co + cb + 32) = s_; }                  \
        { s16x4 s_; s_.x = (short)f2bf(acc3[0]); s_.y = (short)f2bf(acc3[1]); \
          s_.z = (short)f2bf(acc3[2]); s_.w = (short)f2bf(acc3[3]);        \
          *reinterpret_cast<s16x4*>(co + cb + 48) = s_; }                  \
        { s16x4 s_; s_.x = (short)f2bf(acc4[0]); s_.y = (short)f2bf(acc4[1]); \
          s_.z = (short)f2bf(acc4[2]); s_.w = (short)f2bf(acc4[3]);        \
          *reinterpret_cast<s16x4*>(co + cb + 64) = s_; } }

    // ================= prologue =================
    WISSUE(wv0, 0)                           // out: W0:9
    {
#pragma unroll
        for (int r = 0; r < 15; ++r) {       // SLOTS: 15 gl_lds/thread
            const int u   = tid + r * 512;
            const int s   = u / 1920;
            const int rem = u - s * 1920;
            const int pl  = rem / 640;
            const int cu  = rem - pl * 640;
            const short* src = xc + (size_t)((i + pl) * HP + (j0 + s)) * PLANE + cu * 8;
            gl_lds16(src, Sl + (size_t)u * 8);
        }
        SB();
    }                                        // out: W0:9, S:15
    VM(15)                                   // W0 done
    SCATTER(wv0)
    WISSUE(wv1, 1)                           // out: S:15, W1:9
    VM(9)                                    // S done (W1 in flight)
    LG0BAR()                                 // WL=w(0), slots 0-3 ready

    // ================= phase 0 =================
    COMPUTE(0) STORE(0)
    BARA()
    VM(0)                                    // W1 arrived
    SCATTER(wv1)
    WISSUE(wv0, 2)                           // out: W2:9
    LG0BAR()                                 // WL=w(1)

    // ================= phase 1 =================
    RISSUE(0)                                // col j0+4 -> slot 0; out: W2:9, R0:4
    COMPUTE(1) STORE(1)
    BARA()
    VM(4)                                    // W2 done (R0 may remain)
    SCATTER(wv0)
    WISSUE(wv1, 3)                           // out: R0:4, W3:9
    VM(9)                                    // R0 done
    LG0BAR()                                 // WL=w(2), slot0 ready

    // ================= phase 2 =================
    RISSUE(1)                                // col j0+5 -> slot 1; out: W3:9, R1:4
    COMPUTE(2) STORE(2)
    BARA()
    VM(4)                                    // W3 done
    SCATTER(wv1)
    VM(0)                                    // R1 done
    LG0BAR()                                 // WL=w(3), slot1 ready

    // ================= phase 3 =================
    COMPUTE(3) STORE(3)

#undef WISSUE
#undef SCATTER
#undef RISSUE
#undef COMPUTE
#undef STORE
}

// ---- t2 ----
__global__ __launch_bounds__(256) void t2_kernel(
    const short* __restrict__ co,
    const float* __restrict__ bias,
    float* __restrict__ out)
{
    __shared__ short tl[32][36];
    const int b    = blockIdx.x;          // 10240 = o(64) * bkT(5) * pixT(32)
    const int o    = b & 63;
    const int rest = b >> 6;
    const int bkT  = rest % 5;
    const int pixT = rest / 5;
    const int tid  = threadIdx.x;
    {
        const int p  = tid >> 3;
        const int bq = tid & 7;
        const int pix = pixT * 32 + p;
        const s16x4 v = *reinterpret_cast<const s16x4*>(
            co + ((size_t)pix * COUT + o) * NBK + bkT * 32 + bq * 4);
        *reinterpret_cast<s16x4*>(&tl[p][bq * 4]) = v;
    }
    __syncthreads();
    {
        const int bb = tid >> 3;
        const int pq = tid & 7;
        const int bk = bkT * 32 + bb;
        const int k  = bk % 10;
        const size_t pbase = (size_t)pixT * 32 + pq * 4;
        const float4 bv = *reinterpret_cast<const float4*>(
            bias + ((size_t)(k * COUT + o) << 10) + pbase);
        float4 r;
        r.x = __uint_as_float(((unsigned)(unsigned short)tl[pq * 4 + 0][bb]) << 16) + bv.x;
        r.y = __uint_as_float(((unsigned)(unsigned short)tl[pq * 4 + 1][bb]) << 16) + bv.y;
        r.z = __uint_as_float(((unsigned)(unsigned short)tl[pq * 4 + 2][bb]) << 16) + bv.z;
        r.w = __uint_as_float(((unsigned)(unsigned short)tl[pq * 4 + 3][bb]) << 16) + bv.w;
        *reinterpret_cast<float4*>(out + ((size_t)(bk * COUT + o) << 10) + pbase) = r;
    }
}

// ================= R3 fallback (proven; needs 10 MB ws) =================
__global__ __launch_bounds__(256) void xpose_kernel(
    const float* __restrict__ x, short* __restrict__ xc)
{
    __shared__ short tile[HW][36];
    const int bid = blockIdx.x;
    const int bk  = bid >> 5;
    const int h   = bid & 31;
    const int tid = threadIdx.x;
    {
        const int c  = tid >> 3;
        const int w4 = (tid & 7) * 4;
        const float4 v = *reinterpret_cast<const float4*>(
            x + (size_t)(bk * 32 + c) * 1024 + h * 32 + w4);
        tile[w4 + 0][c] = (short)f2bf(v.x);
        tile[w4 + 1][c] = (short)f2bf(v.y);
        tile[w4 + 2][c] = (short)f2bf(v.z);
        tile[w4 + 3][c] = (short)f2bf(v.w);
    }
    __syncthreads();
    {
        const int w  = tid >> 3;
        const int cq = tid & 7;
        const uint2 pk = *reinterpret_cast<const uint2*>(&tile[w][cq * 4]);
        *reinterpret_cast<uint2*>(
            xc + ((size_t)(bk * 1024 + h * 32 + w) * 32 + cq * 4)) = pk;
    }
}

__global__ __launch_bounds__(512, 4) void local2d_mfma2_kernel(
    const short* __restrict__ xc,
    const float* __restrict__ w,
    const float* __restrict__ bias,
    float* __restrict__ out)
{
    __shared__ short Wl[COUT * FPAD];
    const int hb  = blockIdx.x;
    const int lb  = (hb & 7) * 128 + (hb >> 3);
    const int i   = lb >> 5;
    const int j   = lb & 31;
    const int pix = i * HW + j;
    const int tid = threadIdx.x;
    {
        const float* wp = w + (size_t)pix * (COUT * FDIM);
#pragma unroll
        for (int p = 0; p < 9; ++p) {
            const int g  = tid + p * 512;
            const int o  = g / 72;
            const int f4 = (g - o * 72) * 4;
            const float4 v = *reinterpret_cast<const float4*>(wp + o * FDIM + f4);
            const float vv[4] = {v.x, v.y, v.z, v.w};
            short* wrow = &Wl[o * FPAD];
#pragma unroll
            for (int e = 0; e < 4; ++e) {
                const int f    = f4 + e;
                const int c    = f / 9;
                const int cell = f - c * 9;
                wrow[cell * 32 + c] = (short)f2bf(vv[e]);
            }
        }
    }
    __syncthreads();
    const int wave = tid >> 6;
    const int lane = tid & 63;
    const int nt   = wave & 3;
    const int mh   = wave >> 2;
    const int l15  = lane & 15;
    const int lg8  = (lane >> 4) * 8;
    f32x4 acc[5];
#pragma unroll
    for (int mt = 0; mt < 5; ++mt)
#pragma unroll
        for (int r = 0; r < 4; ++r) acc[mt][r] = 0.f;
    const short* xb[5];
#pragma unroll
    for (int mt = 0; mt < 5; ++mt) {
        const int bk = mh * 80 + mt * 16 + l15;
        xb[mt] = xc + (size_t)bk * (HW * HW * CIN) + lg8;
    }
    const short* bp = &Wl[(nt * 16 + l15) * FPAD + lg8];
#pragma unroll
    for (int kc = 0; kc < 9; ++kc) {
        const int kh = kc / 3;
        const int kw = kc - kh * 3;
        const int ih = i - 1 + kh;
        const int jw = j - 1 + kw;
        if ((unsigned)ih >= (unsigned)HW || (unsigned)jw >= (unsigned)HW)
            continue;
        const bf16x8 b = *reinterpret_cast<const bf16x8*>(bp + kc * 32);
        const int xoff = (ih * HW + jw) * CIN;
#pragma unroll
        for (int mt = 0; mt < 5; ++mt) {
            const bf16x8 a = *reinterpret_cast<const bf16x8*>(xb[mt] + xoff);
            acc[mt] = __builtin_amdgcn_mfma_f32_16x16x32_bf16(a, b, acc[mt], 0, 0, 0);
        }
    }
    const int o  = nt * 16 + l15;
    const int r0 = (lane >> 4) * 4;
#pragma unroll
    for (int mt = 0; mt < 5; ++mt) {
        const int bk0 = mh * 80 + mt * 16 + r0;
#pragma unroll
        for (int r = 0; r < 4; ++r) {
            const int bk = bk0 + r;
            const int k  = bk % 10;
            out[((size_t)(bk * COUT + o) << 10) + pix] =
                acc[mt][r] + bias[((size_t)(k * COUT + o) << 10) + pix];
        }
    }
}

extern "C" void kernel_launch(void* const* d_in, const int* in_sizes, int n_in,
                              void* d_out, int out_size, void* d_ws, size_t ws_size,
                              hipStream_t stream) {
    const float* x    = (const float*)d_in[0];
    const float* w    = (const float*)d_in[1];
    const float* bias = (const float*)d_in[2];
    float* out        = (float*)d_out;

    if (ws_size >= XC_BYTES + CO_BYTES) {
        short* xc = (short*)d_ws;
        short* co = (short*)((char*)d_ws + XC_BYTES);
        hipLaunchKernelGGL(hz_kernel, dim3(132), dim3(256), 0, stream, xc);
        hipLaunchKernelGGL(t1_kernel, dim3(5120), dim3(256), 0, stream, x, xc);
        hipLaunchKernelGGL(local2d_p_kernel, dim3(256), dim3(512), 0, stream,
                           xc, w, co);
        hipLaunchKernelGGL(t2_kernel, dim3(10240), dim3(256), 0, stream,
                           co, bias, out);
    } else {
        short* xc = (short*)d_ws;
        hipLaunchKernelGGL(xpose_kernel, dim3(5120), dim3(256), 0, stream, x, xc);
        hipLaunchKernelGGL(local2d_mfma2_kernel, dim3(1024), dim3(512), 0, stream,
                           xc, w, bias, out);
    }
}